// Round 5
// baseline (394.821 us; speedup 1.0000x reference)
//
#include <hip/hip_runtime.h>
#include <stdint.h>
#include <math.h>

#define BB 16
#define NN 100000
#define DD 25
#define CC 20
#define KK 500
#define NCAND 2048
#define NBIN 5120
#define EXPBASE (122 << 10)   // min f32 exponent of a score in (0.05, 1)
#define BPB 391               // stage-A blocks per batch (391*256 >= 100000)
#define GB3 98                // stage-A3 blocks per batch (98*1024 >= 100000)
#define NWAVE 16
#define THRC 0.05
#define THRN 0.5

// Exact f64 score, replicating reference op order.
__device__ __forceinline__ double score_f64(const float* row) {
    double m = (double)row[5];
#pragma unroll
    for (int i = 1; i < CC; ++i) m = fmax(m, (double)row[5 + i]);
    double s = 0.0;
#pragma unroll
    for (int i = 0; i < CC; ++i) s += exp((double)row[5 + i] - m);
    double conf = 1.0 / (1.0 + exp(-(double)row[4]));
    return conf * (1.0 / s);
}

// A: scores -> sc64; per-batch 5120-bin histogram of f32-key top bits.
__global__ __launch_bounds__(256) void score_kernel(const float* __restrict__ outs,
                                                    unsigned long long* __restrict__ sc64,
                                                    uint32_t* __restrict__ ghist) {
    const int b = blockIdx.x / BPB;
    const int lb = blockIdx.x % BPB;
    const int start = lb << 8;
    int nrows = NN - start;
    if (nrows > 256) nrows = 256;
    __shared__ float tile[256 * DD];
    const float4* src = (const float4*)(outs + ((size_t)b * NN + start) * DD);
    const int nf4 = (nrows * DD) >> 2;  // 25*nrows always divisible by 4 here
    float4* dst4 = (float4*)tile;
    for (int i = threadIdx.x; i < nf4; i += 256) dst4[i] = src[i];
    __syncthreads();
    if ((int)threadIdx.x < nrows) {
        const float* row = tile + threadIdx.x * DD;
        double sc = score_f64(row);
        unsigned long long s = 0ULL;
        if (sc > THRC) {
            s = (unsigned long long)__double_as_longlong(sc);
            uint32_t key = __float_as_uint((float)sc);  // RN is monotone
            int bin = (int)(key >> 13) - EXPBASE;
            bin = bin < 0 ? 0 : (bin > NBIN - 1 ? NBIN - 1 : bin);
            atomicAdd(&ghist[b * NBIN + bin], 1u);
        }
        sc64[(size_t)b * NN + start + threadIdx.x] = s;
    }
}

// A2: suffix-scan histogram -> threshold key T' and total positive count.
__global__ __launch_bounds__(1024) void scan_kernel(const uint32_t* __restrict__ ghist,
                                                    uint32_t* __restrict__ meta) {
    const int b = blockIdx.x;
    const int tid = threadIdx.x;
    __shared__ uint32_t h[NBIN];
    __shared__ int sh_b;
    for (int i = tid; i < NBIN; i += 1024) h[i] = ghist[b * NBIN + i];
    __syncthreads();
    // suffix sums: h[v] = sum_{v'>=v} count
    for (int off = 1; off < NBIN; off <<= 1) {
        uint32_t t0[5];
#pragma unroll
        for (int k = 0; k < 5; ++k) {
            int v = tid + k * 1024;
            uint32_t s = h[v];
            int u = v + off;
            if (u < NBIN) s += h[u];
            t0[k] = s;
        }
        __syncthreads();
#pragma unroll
        for (int k = 0; k < 5; ++k) h[tid + k * 1024] = t0[k];
        __syncthreads();
    }
    // largest bin b* with suffix >= KK
#pragma unroll
    for (int k = 0; k < 5; ++k) {
        int v = tid + k * 1024;
        if (h[v] >= KK && (v == NBIN - 1 || h[v + 1] < KK)) sh_b = v;
    }
    __syncthreads();
    if (tid == 0) {
        uint32_t tot = h[0];
        uint32_t T = (tot >= KK) ? (uint32_t)((EXPBASE + sh_b) << 13) : 1u;
        meta[2 * b] = T;
        meta[2 * b + 1] = tot;
    }
}

// A3: full-chip compaction of candidates (key >= T') into per-batch lists.
__global__ __launch_bounds__(1024) void gather_kernel(const unsigned long long* __restrict__ sc64,
                                                      const uint32_t* __restrict__ meta,
                                                      uint32_t* __restrict__ cnt,
                                                      unsigned long long* __restrict__ cand64,
                                                      uint32_t* __restrict__ candidx) {
    const int b = blockIdx.x / GB3;
    const int i = (blockIdx.x % GB3) * 1024 + threadIdx.x;
    if (i >= NN) return;
    unsigned long long s = sc64[(size_t)b * NN + i];
    if (s == 0ULL) return;
    uint32_t key = __float_as_uint((float)__longlong_as_double((long long)s));
    if (key >= meta[2 * b]) {
        uint32_t pos = atomicAdd(&cnt[b], 1u);
        if (pos < NCAND) {
            cand64[b * NCAND + pos] = s;
            candidx[b * NCAND + pos] = (uint32_t)i;
        }
    }
}

// B: exact rank-based top-500, decode, NMS, outputs. Tiny inputs only.
__global__ __launch_bounds__(1024) void nms_kernel(const float* __restrict__ outs,
                                                   const unsigned long long* __restrict__ sc64,
                                                   const uint32_t* __restrict__ cnt,
                                                   const unsigned long long* __restrict__ cand64,
                                                   const uint32_t* __restrict__ candidx,
                                                   float* __restrict__ out) {
    const int b = blockIdx.x;
    const int tid = threadIdx.x;
    const int wave = tid >> 6;
    const int lane = tid & 63;
    const unsigned long long* sb = sc64 + (size_t)b * NN;

    __shared__ unsigned long long ckey[NCAND];
    __shared__ uint32_t cidx[NCAND];
    __shared__ double dsc[KK];
    __shared__ uint32_t sid[KK];
    __shared__ double bxl[KK], bxt[KK], bxr[KK], bxd[KK];
    __shared__ int lab[KK];
    __shared__ unsigned long long sup[KK][8];
    __shared__ unsigned long long keepw[8];
    __shared__ uint32_t zpref[1024];
    __shared__ uint32_t zbase;

    uint32_t cr = cnt[b];
    const int nc = (int)(cr < NCAND ? cr : NCAND);
    for (int i = tid; i < nc; i += 1024) {
        ckey[i] = cand64[b * NCAND + i];
        cidx[i] = candidx[b * NCAND + i];
    }
    __syncthreads();

    // exact rank among candidates: (f64 score desc, idx asc); unique ranks
    for (int c = tid; c < nc; c += 1024) {
        unsigned long long kc = ckey[c];
        uint32_t ic = cidx[c];
        int r = 0;
        for (int j = 0; j < nc; ++j) {
            unsigned long long kj = ckey[j];
            uint32_t ij = cidx[j];
            r += (kj > kc) || (kj == kc && ij < ic);
        }
        if (r < KK) {
            dsc[r] = __longlong_as_double((long long)kc);
            sid[r] = ic;
        }
    }
    // fallback (< 500 positives): fill remaining slots with lowest-index zeros
    if (nc < KK) {
        for (int i = tid; i < KK; i += 1024)
            if (i >= nc) dsc[i] = 0.0;
        if (tid == 0) zbase = 0;
        __syncthreads();
        const uint32_t needz = (uint32_t)(KK - nc);
        for (int c0 = 0; c0 < NN; c0 += 1024) {
            int i = c0 + tid;
            uint32_t z = (i < NN && sb[i] == 0ULL) ? 1u : 0u;
            zpref[tid] = z;
            __syncthreads();
            for (int off = 1; off < 1024; off <<= 1) {
                uint32_t v = (tid >= off) ? zpref[tid - off] : 0u;
                __syncthreads();
                zpref[tid] += v;
                __syncthreads();
            }
            uint32_t pos = zbase + zpref[tid] - z;
            if (z && pos < needz) sid[nc + pos] = (uint32_t)i;
            __syncthreads();
            if (tid == 0) zbase += zpref[1023];
            __syncthreads();
            if (zbase >= needz) break;
        }
    }
    __syncthreads();

    // decode 500 rows (f64)
    for (int i = tid; i < KK; i += 1024) {
        uint32_t idx = sid[i];
        const float* row = outs + ((size_t)b * NN + idx) * DD;
        double cx = 1.0 / (1.0 + exp(-(double)row[0]));
        double cy = 1.0 / (1.0 + exp(-(double)row[1]));
        double w = 1.0 / (1.0 + exp(-(double)row[2]));
        double h = 1.0 / (1.0 + exp(-(double)row[3]));
        bxl[i] = cx - 0.5 * w;
        bxt[i] = cy - 0.5 * h;
        bxr[i] = cx + 0.5 * w;
        bxd[i] = cy + 0.5 * h;
        float mm = row[5];
        int am = 0;
#pragma unroll
        for (int c = 1; c < CC; ++c) {
            float v = row[5 + c];
            if (v > mm) { mm = v; am = c; }
        }
        lab[i] = am;
    }
    __syncthreads();

    // suppression bitmask, transposed ballot (conflict-light)
    for (int p = wave; p < KK * 8; p += NWAVE) {
        int i = p >> 3;
        int w = p & 7;
        int j = w * 64 + lane;
        bool sbit = false;
        if (j < KK && lab[j] == lab[i]) {
            double l1 = bxl[i], t1 = bxt[i], r1 = bxr[i], d1 = bxd[i];
            double a1 = fmax(r1 - l1, 0.0) * fmax(d1 - t1, 0.0);
            double l2 = bxl[j], t2 = bxt[j], r2 = bxr[j], d2 = bxd[j];
            double iw = fmax(fmin(r1, r2) - fmax(l1, l2), 0.0);
            double ih = fmax(fmin(d1, d2) - fmax(t1, t2), 0.0);
            double inter = iw * ih;
            double a2 = fmax(r2 - l2, 0.0) * fmax(d2 - t2, 0.0);
            double uni = a1 + a2 - inter;
            double iou = inter / fmax(uni, 1e-9);
            sbit = iou > THRN;
        }
        unsigned long long word = __ballot(sbit);
        if (lane == 0) sup[i][w] = word;
    }
    __syncthreads();

    // wave-parallel greedy NMS: 8 chunks of 64, shfl-serial inside
    if (tid < 64) {
        unsigned long long kept[8];
#pragma unroll
        for (int w = 0; w < 8; ++w) kept[w] = 0ULL;
#pragma unroll
        for (int c = 0; c < 8; ++c) {
            int i = c * 64 + lane;
            unsigned long long sprev = 0ULL;
            unsigned long long myw = 0ULL;
            bool vi = false;
            if (i < KK) {
#pragma unroll
                for (int w = 0; w < 8; ++w)
                    if (w < c) sprev |= sup[i][w] & kept[w];
                myw = sup[i][c];
                vi = dsc[i] > THRC;
            }
            unsigned long long ck = 0ULL;
            for (int j = 0; j < 64; ++j) {
                int myk = (vi && sprev == 0ULL && (myw & ck) == 0ULL) ? 1 : 0;
                int kj = __shfl(myk, j);
                if (kj) ck |= (1ULL << j);
            }
            kept[c] = ck;
        }
        if (lane == 0) {
#pragma unroll
            for (int w = 0; w < 8; ++w) keepw[w] = kept[w];
        }
    }
    __syncthreads();

    // outputs: [ids | boxes | labels | scores] flat f32 concat
    float* out_ids = out;
    float* out_boxes = out + BB * KK;
    float* out_labels = out + BB * KK * 5;
    float* out_scores = out + BB * KK * 6;
    for (int i = tid; i < KK; i += 1024) {
        bool keep = (keepw[i >> 6] >> (i & 63)) & 1ULL;
        out_ids[b * KK + i] = (float)b;
        float* bo = out_boxes + ((size_t)b * KK + i) * 4;
        bo[0] = (float)bxl[i];
        bo[1] = (float)bxt[i];
        bo[2] = (float)bxr[i];
        bo[3] = (float)bxd[i];
        out_labels[b * KK + i] = keep ? (float)lab[i] : -1.0f;
        out_scores[b * KK + i] = keep ? (float)dsc[i] : 0.0f;
    }
}

extern "C" void kernel_launch(void* const* d_in, const int* in_sizes, int n_in,
                              void* d_out, int out_size, void* d_ws, size_t ws_size,
                              hipStream_t stream) {
    const float* outs = (const float*)d_in[0];
    float* out = (float*)d_out;
    char* ws = (char*)d_ws;

    unsigned long long* sc64 = (unsigned long long*)ws;               // 12.8 MB
    size_t off = (size_t)BB * NN * 8;
    unsigned long long* cand64 = (unsigned long long*)(ws + off);     // 256 KB
    off += (size_t)BB * NCAND * 8;
    size_t ghist_off = off;
    uint32_t* ghist = (uint32_t*)(ws + off);                          // 320 KB
    off += (size_t)BB * NBIN * 4;
    uint32_t* cnt = (uint32_t*)(ws + off);                            // 64 B
    off += BB * 4;
    uint32_t* meta = (uint32_t*)(ws + off);                           // 128 B
    off += BB * 2 * 4;
    uint32_t* candidx = (uint32_t*)(ws + off);                        // 128 KB

    // zero histogram + counters (adjacent) each call
    hipMemsetAsync(ws + ghist_off, 0, (size_t)BB * NBIN * 4 + BB * 4, stream);

    score_kernel<<<BB * BPB, 256, 0, stream>>>(outs, sc64, ghist);
    scan_kernel<<<BB, 1024, 0, stream>>>(ghist, meta);
    gather_kernel<<<BB * GB3, 1024, 0, stream>>>(sc64, meta, cnt, cand64, candidx);
    nms_kernel<<<BB, 1024, 0, stream>>>(outs, sc64, cnt, cand64, candidx, out);
}

// Round 6
// 338.893 us; speedup vs baseline: 1.1650x; 1.1650x over previous
//
#include <hip/hip_runtime.h>
#include <stdint.h>
#include <math.h>

#define BB 16
#define NN 100000
#define DD 25
#define CC 20
#define KK 500
#define NCAND 2048
#define NBIN 5120
#define EXPBASE (122 << 10)   // min f32 exponent field of a score in (0.05, 1)
#define BPB 391               // score blocks per batch (391*256 >= 100000)
#define GB3 98                // gather blocks per batch (98*1024 >= 100000)
#define THRC 0.05
#define THRN 0.5

// Exact f64 score, replicating reference op order.
__device__ __forceinline__ double score_f64(const float* row) {
    double m = (double)row[5];
#pragma unroll
    for (int i = 1; i < CC; ++i) m = fmax(m, (double)row[5 + i]);
    double s = 0.0;
#pragma unroll
    for (int i = 0; i < CC; ++i) s += exp((double)row[5 + i] - m);
    double conf = 1.0 / (1.0 + exp(-(double)row[4]));
    return conf * (1.0 / s);
}

__device__ __forceinline__ void decode_box(const float* row, double* o) {
    double cx = 1.0 / (1.0 + exp(-(double)row[0]));
    double cy = 1.0 / (1.0 + exp(-(double)row[1]));
    double w = 1.0 / (1.0 + exp(-(double)row[2]));
    double h = 1.0 / (1.0 + exp(-(double)row[3]));
    o[0] = cx - 0.5 * w;
    o[1] = cy - 0.5 * h;
    o[2] = cx + 0.5 * w;
    o[3] = cy + 0.5 * h;
}

__device__ __forceinline__ int argmax_cls(const float* row) {
    float mm = row[5];
    int am = 0;
#pragma unroll
    for (int c = 1; c < CC; ++c) {
        float v = row[5 + c];
        if (v > mm) { mm = v; am = c; }
    }
    return am;
}

// A: scores -> sc64; per-batch histogram with LDS pre-aggregation (no hot-bin
// global-atomic serialization).
__global__ __launch_bounds__(256) void score_kernel(const float* __restrict__ outs,
                                                    unsigned long long* __restrict__ sc64,
                                                    uint32_t* __restrict__ ghist) {
    __shared__ float tile[256 * DD];
    __shared__ uint32_t lhist[NBIN];
    const int b = blockIdx.x / BPB;
    const int lb = blockIdx.x % BPB;
    const int start = lb << 8;
    int nrows = NN - start;
    if (nrows > 256) nrows = 256;
    const float4* src = (const float4*)(outs + ((size_t)b * NN + start) * DD);
    const int nf4 = (nrows * DD) >> 2;  // 25*nrows divisible by 4 (nrows 256 or 160)
    float4* dst4 = (float4*)tile;
    for (int i = threadIdx.x; i < nf4; i += 256) dst4[i] = src[i];
    for (int i = threadIdx.x; i < NBIN; i += 256) lhist[i] = 0;
    __syncthreads();
    if ((int)threadIdx.x < nrows) {
        const float* row = tile + threadIdx.x * DD;
        double sc = score_f64(row);
        unsigned long long s = 0ULL;
        if (sc > THRC) {
            s = (unsigned long long)__double_as_longlong(sc);
            uint32_t key = __float_as_uint((float)sc);  // RN is monotone
            int bin = (int)(key >> 13) - EXPBASE;
            bin = bin < 0 ? 0 : (bin > NBIN - 1 ? NBIN - 1 : bin);
            atomicAdd(&lhist[bin], 1u);
        }
        sc64[(size_t)b * NN + start + threadIdx.x] = s;
    }
    __syncthreads();
    for (int i = threadIdx.x; i < NBIN; i += 256) {
        uint32_t v = lhist[i];
        if (v) atomicAdd(&ghist[b * NBIN + i], v);
    }
}

// A2: suffix-scan histogram -> threshold key T' (count(key>=T') >= 500).
__global__ __launch_bounds__(1024) void scan_kernel(const uint32_t* __restrict__ ghist,
                                                    uint32_t* __restrict__ meta) {
    const int b = blockIdx.x;
    const int tid = threadIdx.x;
    __shared__ uint32_t h[NBIN];
    __shared__ int sh_b;
    for (int i = tid; i < NBIN; i += 1024) h[i] = ghist[b * NBIN + i];
    __syncthreads();
    for (int off = 1; off < NBIN; off <<= 1) {
        uint32_t t0[5];
#pragma unroll
        for (int k = 0; k < 5; ++k) {
            int v = tid + k * 1024;
            uint32_t s = h[v];
            int u = v + off;
            if (u < NBIN) s += h[u];
            t0[k] = s;
        }
        __syncthreads();
#pragma unroll
        for (int k = 0; k < 5; ++k) h[tid + k * 1024] = t0[k];
        __syncthreads();
    }
#pragma unroll
    for (int k = 0; k < 5; ++k) {
        int v = tid + k * 1024;
        if (h[v] >= KK && (v == NBIN - 1 || h[v + 1] < KK)) sh_b = v;
    }
    __syncthreads();
    if (tid == 0) {
        uint32_t tot = h[0];
        uint32_t T = (tot >= KK) ? (uint32_t)((EXPBASE + sh_b) << 13) : 1u;
        meta[2 * b] = T;
        meta[2 * b + 1] = tot;
    }
}

// A3: full-chip compaction (key >= T') + box/label decode for candidates.
__global__ __launch_bounds__(1024) void gather_kernel(const float* __restrict__ outs,
                                                      const unsigned long long* __restrict__ sc64,
                                                      const uint32_t* __restrict__ meta,
                                                      uint32_t* __restrict__ cnt,
                                                      unsigned long long* __restrict__ cand64,
                                                      uint32_t* __restrict__ candidx,
                                                      double* __restrict__ cbox,
                                                      int* __restrict__ clab) {
    const int b = blockIdx.x / GB3;
    const int i = (blockIdx.x % GB3) * 1024 + threadIdx.x;
    if (i >= NN) return;
    unsigned long long s = sc64[(size_t)b * NN + i];
    if (s == 0ULL) return;
    uint32_t key = __float_as_uint((float)__longlong_as_double((long long)s));
    if (key < meta[2 * b]) return;
    uint32_t pos = atomicAdd(&cnt[b], 1u);
    if (pos >= NCAND) return;
    cand64[b * NCAND + pos] = s;
    candidx[b * NCAND + pos] = (uint32_t)i;
    const float* row = outs + ((size_t)b * NN + i) * DD;
    decode_box(row, cbox + ((size_t)b * NCAND + pos) * 4);
    clab[b * NCAND + pos] = argmax_cls(row);
}

// R: exact unique rank (f64 desc, idx asc) -> sorted top-500 arrays.
__global__ __launch_bounds__(1024) void rank_kernel(const float* __restrict__ outs,
                                                    const unsigned long long* __restrict__ sc64,
                                                    const uint32_t* __restrict__ cnt,
                                                    const unsigned long long* __restrict__ cand64,
                                                    const uint32_t* __restrict__ candidx,
                                                    const double* __restrict__ cbox,
                                                    const int* __restrict__ clab,
                                                    double* __restrict__ sdsc,
                                                    double* __restrict__ sbox,
                                                    int* __restrict__ slab) {
    const int b = blockIdx.x;
    const int tid = threadIdx.x;
    __shared__ unsigned long long ckey[NCAND];
    __shared__ uint32_t cidx[NCAND];
    __shared__ uint32_t zpref[1024];
    __shared__ uint32_t zbase;
    uint32_t cr = cnt[b];
    const int nc = (int)(cr < NCAND ? cr : NCAND);
    for (int i = tid; i < nc; i += 1024) {
        ckey[i] = cand64[b * NCAND + i];
        cidx[i] = candidx[b * NCAND + i];
    }
    __syncthreads();
    for (int c = tid; c < nc; c += 1024) {
        unsigned long long kc = ckey[c];
        uint32_t ic = cidx[c];
        int r = 0;
        int j = 0;
        for (; j + 8 <= nc; j += 8) {
#pragma unroll
            for (int u = 0; u < 8; ++u) {  // 8 independent LDS reads -> one wait
                unsigned long long kj = ckey[j + u];
                uint32_t ij = cidx[j + u];
                r += (int)((kj > kc) || (kj == kc && ij < ic));
            }
        }
        for (; j < nc; ++j) {
            unsigned long long kj = ckey[j];
            uint32_t ij = cidx[j];
            r += (int)((kj > kc) || (kj == kc && ij < ic));
        }
        if (r < KK) {
            sdsc[b * KK + r] = __longlong_as_double((long long)kc);
            const double* cb = cbox + ((size_t)b * NCAND + c) * 4;
            double* sp = sbox + ((size_t)b * KK + r) * 4;
            sp[0] = cb[0]; sp[1] = cb[1]; sp[2] = cb[2]; sp[3] = cb[3];
            slab[b * KK + r] = clab[b * NCAND + c];
        }
    }
    // fallback (< 500 positives): fill slots with lowest-index zero-score rows
    if (nc < KK) {
        const unsigned long long* sb = sc64 + (size_t)b * NN;
        if (tid == 0) zbase = 0;
        __syncthreads();
        const uint32_t needz = (uint32_t)(KK - nc);
        for (int c0 = 0; c0 < NN; c0 += 1024) {
            int i = c0 + tid;
            uint32_t z = (i < NN && sb[i] == 0ULL) ? 1u : 0u;
            zpref[tid] = z;
            __syncthreads();
            for (int off = 1; off < 1024; off <<= 1) {
                uint32_t v = (tid >= off) ? zpref[tid - off] : 0u;
                __syncthreads();
                zpref[tid] += v;
                __syncthreads();
            }
            uint32_t pos = zbase + zpref[tid] - z;
            if (z && pos < needz) {
                int r = nc + (int)pos;
                const float* row = outs + ((size_t)b * NN + i) * DD;
                sdsc[b * KK + r] = 0.0;
                decode_box(row, sbox + ((size_t)b * KK + r) * 4);
                slab[b * KK + r] = argmax_cls(row);
            }
            __syncthreads();
            if (tid == 0) zbase += zpref[1023];
            __syncthreads();
            if (zbase >= needz) break;
        }
    }
}

// B: suppression matrix + greedy NMS + outputs (tiny, latency-trimmed).
__global__ __launch_bounds__(1024) void supnms_kernel(const double* __restrict__ sdsc,
                                                      const double* __restrict__ sbox,
                                                      const int* __restrict__ slab,
                                                      float* __restrict__ out) {
    const int b = blockIdx.x;
    const int tid = threadIdx.x;
    const int wave = tid >> 6;
    const int lane = tid & 63;
    __shared__ double bxl[KK], bxt[KK], bxr[KK], bxd[KK];
    __shared__ double dsc[KK];
    __shared__ int lab[KK];
    __shared__ unsigned long long sup[KK][8];
    __shared__ unsigned long long keepw[8];

    for (int i = tid; i < KK; i += 1024) {
        const double* sp = sbox + ((size_t)b * KK + i) * 4;
        bxl[i] = sp[0]; bxt[i] = sp[1]; bxr[i] = sp[2]; bxd[i] = sp[3];
        dsc[i] = sdsc[b * KK + i];
        lab[i] = slab[b * KK + i];
    }
    __syncthreads();

    // sup-build: wave -> (w = wave&7, half = wave>>3). Column-j box loaded ONCE.
    {
        const int w = wave & 7;
        const int half = wave >> 3;
        const int j = w * 64 + lane;
        const bool jv = j < KK;
        double l2 = 0, t2 = 0, r2 = 0, d2 = 0, a2 = 0;
        int lj = -2;
        if (jv) {
            l2 = bxl[j]; t2 = bxt[j]; r2 = bxr[j]; d2 = bxd[j];
            lj = lab[j];
            a2 = fmax(r2 - l2, 0.0) * fmax(d2 - t2, 0.0);
        }
        const int i0 = half * 250, i1 = i0 + 250;
        for (int i = i0; i < i1; ++i) {
            double l1 = bxl[i], t1 = bxt[i], r1 = bxr[i], d1 = bxd[i];  // broadcast
            int li = lab[i];
            bool sbit = false;
            if (jv && lj == li) {
                double a1 = fmax(r1 - l1, 0.0) * fmax(d1 - t1, 0.0);
                double iw = fmax(fmin(r1, r2) - fmax(l1, l2), 0.0);
                double ih = fmax(fmin(d1, d2) - fmax(t1, t2), 0.0);
                double inter = iw * ih;
                double uni = a1 + a2 - inter;
                // iou > 0.5  <=>  inter > 0.5*max(uni,1e-9)  (0.5* is exact)
                sbit = inter > THRN * fmax(uni, 1e-9);
            }
            unsigned long long word = __ballot(sbit);
            if (lane == 0) sup[i][w] = word;
        }
    }
    __syncthreads();

    // wave-parallel greedy NMS: 8 chunks of 64 rows, shfl-serial inside
    if (tid < 64) {
        unsigned long long kept[8];
#pragma unroll
        for (int w = 0; w < 8; ++w) kept[w] = 0ULL;
#pragma unroll
        for (int c = 0; c < 8; ++c) {
            int i = c * 64 + lane;
            unsigned long long sprev = 0ULL;
            unsigned long long myw = 0ULL;
            bool vi = false;
            if (i < KK) {
#pragma unroll
                for (int w = 0; w < 8; ++w)
                    if (w < c) sprev |= sup[i][w] & kept[w];
                myw = sup[i][c];
                vi = dsc[i] > THRC;
            }
            unsigned long long ck = 0ULL;
            for (int j = 0; j < 64; ++j) {
                int myk = (vi && sprev == 0ULL && (myw & ck) == 0ULL) ? 1 : 0;
                int kj = __shfl(myk, j);
                if (kj) ck |= (1ULL << j);
            }
            kept[c] = ck;
        }
        if (lane == 0) {
#pragma unroll
            for (int w = 0; w < 8; ++w) keepw[w] = kept[w];
        }
    }
    __syncthreads();

    // outputs: [ids | boxes | labels | scores] flat f32 concat
    float* out_ids = out;
    float* out_boxes = out + BB * KK;
    float* out_labels = out + BB * KK * 5;
    float* out_scores = out + BB * KK * 6;
    for (int i = tid; i < KK; i += 1024) {
        bool keep = (keepw[i >> 6] >> (i & 63)) & 1ULL;
        out_ids[b * KK + i] = (float)b;
        float* bo = out_boxes + ((size_t)b * KK + i) * 4;
        bo[0] = (float)bxl[i];
        bo[1] = (float)bxt[i];
        bo[2] = (float)bxr[i];
        bo[3] = (float)bxd[i];
        out_labels[b * KK + i] = keep ? (float)lab[i] : -1.0f;
        out_scores[b * KK + i] = keep ? (float)dsc[i] : 0.0f;
    }
}

extern "C" void kernel_launch(void* const* d_in, const int* in_sizes, int n_in,
                              void* d_out, int out_size, void* d_ws, size_t ws_size,
                              hipStream_t stream) {
    const float* outs = (const float*)d_in[0];
    float* out = (float*)d_out;
    char* ws = (char*)d_ws;

    unsigned long long* sc64 = (unsigned long long*)ws;            // 12.8 MB
    size_t off = (size_t)BB * NN * 8;
    unsigned long long* cand64 = (unsigned long long*)(ws + off);  // 256 KB
    off += (size_t)BB * NCAND * 8;
    double* cbox = (double*)(ws + off);                            // 1 MB
    off += (size_t)BB * NCAND * 4 * 8;
    double* sbox = (double*)(ws + off);                            // 256 KB
    off += (size_t)BB * KK * 4 * 8;
    double* sdsc = (double*)(ws + off);                            // 64 KB
    off += (size_t)BB * KK * 8;
    size_t ghist_off = off;
    uint32_t* ghist = (uint32_t*)(ws + off);                       // 320 KB [memset]
    off += (size_t)BB * NBIN * 4;
    uint32_t* cnt = (uint32_t*)(ws + off);                         // 64 B   [memset]
    off += BB * 4;
    uint32_t* meta = (uint32_t*)(ws + off);                        // 128 B
    off += BB * 2 * 4;
    uint32_t* candidx = (uint32_t*)(ws + off);                     // 128 KB
    off += (size_t)BB * NCAND * 4;
    int* clab = (int*)(ws + off);                                  // 128 KB
    off += (size_t)BB * NCAND * 4;
    int* slab = (int*)(ws + off);                                  // 32 KB

    hipMemsetAsync(ws + ghist_off, 0, (size_t)BB * NBIN * 4 + BB * 4, stream);

    score_kernel<<<BB * BPB, 256, 0, stream>>>(outs, sc64, ghist);
    scan_kernel<<<BB, 1024, 0, stream>>>(ghist, meta);
    gather_kernel<<<BB * GB3, 1024, 0, stream>>>(outs, sc64, meta, cnt, cand64, candidx, cbox, clab);
    rank_kernel<<<BB, 1024, 0, stream>>>(outs, sc64, cnt, cand64, candidx, cbox, clab, sdsc, sbox, slab);
    supnms_kernel<<<BB, 1024, 0, stream>>>(sdsc, sbox, slab, out);
}

// Round 7
// 260.817 us; speedup vs baseline: 1.5138x; 1.2994x over previous
//
#include <hip/hip_runtime.h>
#include <stdint.h>
#include <math.h>

#define BB 16
#define NN 100000
#define DD 25
#define CC 20
#define KK 500
#define NCAND 2048
#define NBIN 5120
#define EXPBASE (122 << 10)   // min f32 exponent field of a score in (0.049, 1)
#define BPB 391               // score blocks per batch (391*256 >= 100000)
#define GB3 98                // gather blocks per batch (98*1024 >= 100000)
#define THRC 0.05
#define THRN 0.5

// Exact f64 score, replicating reference op order (candidates only).
__device__ __forceinline__ double score_f64(const float* row) {
    double m = (double)row[5];
#pragma unroll
    for (int i = 1; i < CC; ++i) m = fmax(m, (double)row[5 + i]);
    double s = 0.0;
#pragma unroll
    for (int i = 0; i < CC; ++i) s += exp((double)row[5 + i] - m);
    double conf = 1.0 / (1.0 + exp(-(double)row[4]));
    return conf * (1.0 / s);
}

// Fast f32 approx score (error ~32 ulp << histogram bin width of 8192 ulp).
__device__ __forceinline__ float score_f32(const float* row) {
    float m = row[5];
#pragma unroll
    for (int i = 1; i < CC; ++i) m = fmaxf(m, row[5 + i]);
    float s = 0.0f;
#pragma unroll
    for (int i = 0; i < CC; ++i) s += __expf(row[5 + i] - m);
    float conf = 1.0f / (1.0f + __expf(-row[4]));
    return conf / s;
}

__device__ __forceinline__ void decode_box(const float* row, double* o) {
    double cx = 1.0 / (1.0 + exp(-(double)row[0]));
    double cy = 1.0 / (1.0 + exp(-(double)row[1]));
    double w = 1.0 / (1.0 + exp(-(double)row[2]));
    double h = 1.0 / (1.0 + exp(-(double)row[3]));
    o[0] = cx - 0.5 * w;
    o[1] = cy - 0.5 * h;
    o[2] = cx + 0.5 * w;
    o[3] = cy + 0.5 * h;
}

__device__ __forceinline__ int argmax_cls(const float* row) {
    float mm = row[5];
    int am = 0;
#pragma unroll
    for (int c = 1; c < CC; ++c) {
        float v = row[5 + c];
        if (v > mm) { mm = v; am = c; }
    }
    return am;
}

// A: f32 approx keys + per-batch histogram (LDS pre-aggregated). Memory-bound.
__global__ __launch_bounds__(256) void score_kernel(const float* __restrict__ outs,
                                                    uint32_t* __restrict__ keys,
                                                    uint32_t* __restrict__ ghist) {
    __shared__ float tile[256 * DD];
    __shared__ uint32_t lhist[NBIN];
    const int b = blockIdx.x / BPB;
    const int lb = blockIdx.x % BPB;
    const int start = lb << 8;
    int nrows = NN - start;
    if (nrows > 256) nrows = 256;
    const float4* src = (const float4*)(outs + ((size_t)b * NN + start) * DD);
    const int nf4 = (nrows * DD) >> 2;
    float4* dst4 = (float4*)tile;
    for (int i = threadIdx.x; i < nf4; i += 256) dst4[i] = src[i];
    for (int i = threadIdx.x; i < NBIN; i += 256) lhist[i] = 0;
    __syncthreads();
    if ((int)threadIdx.x < nrows) {
        const float* row = tile + threadIdx.x * DD;
        float sc = score_f32(row);
        uint32_t key = 0;
        if (sc > 0.049f) {  // loose pre-mask; exact 0.05 decided in f64 later
            key = __float_as_uint(sc);
            int bin = (int)(key >> 13) - EXPBASE;
            bin = bin < 0 ? 0 : (bin > NBIN - 1 ? NBIN - 1 : bin);
            atomicAdd(&lhist[bin], 1u);
        }
        keys[(size_t)b * NN + start + threadIdx.x] = key;
    }
    __syncthreads();
    for (int i = threadIdx.x; i < NBIN; i += 256) {
        uint32_t v = lhist[i];
        if (v) atomicAdd(&ghist[b * NBIN + i], v);
    }
}

// A2: suffix-scan -> T'' = one bin below the count>=500 edge (safety margin).
__global__ __launch_bounds__(1024) void scan_kernel(const uint32_t* __restrict__ ghist,
                                                    uint32_t* __restrict__ meta) {
    const int b = blockIdx.x;
    const int tid = threadIdx.x;
    __shared__ uint32_t h[NBIN];
    __shared__ int sh_b;
    for (int i = tid; i < NBIN; i += 1024) h[i] = ghist[b * NBIN + i];
    __syncthreads();
    for (int off = 1; off < NBIN; off <<= 1) {
        uint32_t t0[5];
#pragma unroll
        for (int k = 0; k < 5; ++k) {
            int v = tid + k * 1024;
            uint32_t s = h[v];
            int u = v + off;
            if (u < NBIN) s += h[u];
            t0[k] = s;
        }
        __syncthreads();
#pragma unroll
        for (int k = 0; k < 5; ++k) h[tid + k * 1024] = t0[k];
        __syncthreads();
    }
#pragma unroll
    for (int k = 0; k < 5; ++k) {
        int v = tid + k * 1024;
        if (h[v] >= KK && (v == NBIN - 1 || h[v + 1] < KK)) sh_b = v;
    }
    __syncthreads();
    if (tid == 0) {
        uint32_t tot = h[0];
        int b2 = sh_b > 0 ? sh_b - 1 : sh_b;  // margin >> f32 approx error
        uint32_t T = (tot >= KK) ? (uint32_t)((EXPBASE + b2) << 13) : 1u;
        meta[2 * b] = T;
        meta[2 * b + 1] = tot;
    }
}

// A3: compaction (approx key >= T'') + exact f64 score + box/label decode.
__global__ __launch_bounds__(1024) void gather_kernel(const float* __restrict__ outs,
                                                      const uint32_t* __restrict__ keys,
                                                      const uint32_t* __restrict__ meta,
                                                      uint32_t* __restrict__ cnt,
                                                      unsigned long long* __restrict__ cand64,
                                                      uint32_t* __restrict__ candidx,
                                                      double* __restrict__ cbox,
                                                      int* __restrict__ clab) {
    const int b = blockIdx.x / GB3;
    const int i = (blockIdx.x % GB3) * 1024 + threadIdx.x;
    if (i >= NN) return;
    uint32_t key = keys[(size_t)b * NN + i];
    if (key == 0 || key < meta[2 * b]) return;
    uint32_t pos = atomicAdd(&cnt[b], 1u);
    if (pos >= NCAND) return;
    const float* row = outs + ((size_t)b * NN + i) * DD;
    double sc = score_f64(row);
    cand64[b * NCAND + pos] =
        (sc > THRC) ? (unsigned long long)__double_as_longlong(sc) : 0ULL;
    candidx[b * NCAND + pos] = (uint32_t)i;
    decode_box(row, cbox + ((size_t)b * NCAND + pos) * 4);
    clab[b * NCAND + pos] = argmax_cls(row);
}

// R: exact unique rank (f64 desc, idx asc) -> rank-ordered arrays + ids/boxes out.
__global__ __launch_bounds__(1024) void rank_kernel(const float* __restrict__ outs,
                                                    const uint32_t* __restrict__ keys,
                                                    const uint32_t* __restrict__ cnt,
                                                    const unsigned long long* __restrict__ cand64,
                                                    const uint32_t* __restrict__ candidx,
                                                    const double* __restrict__ cbox,
                                                    const int* __restrict__ clab,
                                                    double* __restrict__ sdsc,
                                                    double* __restrict__ sbL, double* __restrict__ sbT,
                                                    double* __restrict__ sbR, double* __restrict__ sbD,
                                                    int* __restrict__ slab,
                                                    float* __restrict__ out) {
    const int b = blockIdx.x;
    const int tid = threadIdx.x;
    __shared__ unsigned long long ckey[NCAND];
    __shared__ uint32_t cidx[NCAND];
    __shared__ uint32_t zpref[1024];
    __shared__ uint32_t zbase;
    float* out_ids = out;
    float* out_boxes = out + BB * KK;
    uint32_t cr = cnt[b];
    const int nc = (int)(cr < NCAND ? cr : NCAND);
    for (int i = tid; i < nc; i += 1024) {
        ckey[i] = cand64[b * NCAND + i];
        cidx[i] = candidx[b * NCAND + i];
    }
    __syncthreads();
    for (int c = tid; c < nc; c += 1024) {
        unsigned long long kc = ckey[c];
        uint32_t ic = cidx[c];
        int r = 0;
        int j = 0;
        for (; j + 8 <= nc; j += 8) {
#pragma unroll
            for (int u = 0; u < 8; ++u) {
                unsigned long long kj = ckey[j + u];
                uint32_t ij = cidx[j + u];
                r += (int)((kj > kc) || (kj == kc && ij < ic));
            }
        }
        for (; j < nc; ++j) {
            unsigned long long kj = ckey[j];
            uint32_t ij = cidx[j];
            r += (int)((kj > kc) || (kj == kc && ij < ic));
        }
        if (r < KK) {
            sdsc[b * KK + r] = __longlong_as_double((long long)kc);
            const double* cb = cbox + ((size_t)b * NCAND + c) * 4;
            sbL[b * KK + r] = cb[0];
            sbT[b * KK + r] = cb[1];
            sbR[b * KK + r] = cb[2];
            sbD[b * KK + r] = cb[3];
            slab[b * KK + r] = clab[b * NCAND + c];
            float* bo = out_boxes + ((size_t)b * KK + r) * 4;
            bo[0] = (float)cb[0]; bo[1] = (float)cb[1];
            bo[2] = (float)cb[2]; bo[3] = (float)cb[3];
        }
    }
    for (int i = tid; i < KK; i += 1024) out_ids[b * KK + i] = (float)b;
    // fallback (< 500 positives): lowest-index zero-key rows fill the rest
    if (nc < KK) {
        const uint32_t* kb = keys + (size_t)b * NN;
        if (tid == 0) zbase = 0;
        __syncthreads();
        const uint32_t needz = (uint32_t)(KK - nc);
        for (int c0 = 0; c0 < NN; c0 += 1024) {
            int i = c0 + tid;
            uint32_t z = (i < NN && kb[i] == 0) ? 1u : 0u;
            zpref[tid] = z;
            __syncthreads();
            for (int off = 1; off < 1024; off <<= 1) {
                uint32_t v = (tid >= off) ? zpref[tid - off] : 0u;
                __syncthreads();
                zpref[tid] += v;
                __syncthreads();
            }
            uint32_t pos = zbase + zpref[tid] - z;
            if (z && pos < needz) {
                int r = nc + (int)pos;
                const float* row = outs + ((size_t)b * NN + i) * DD;
                double o[4];
                decode_box(row, o);
                sdsc[b * KK + r] = 0.0;
                sbL[b * KK + r] = o[0]; sbT[b * KK + r] = o[1];
                sbR[b * KK + r] = o[2]; sbD[b * KK + r] = o[3];
                slab[b * KK + r] = argmax_cls(row);
                float* bo = out_boxes + ((size_t)b * KK + r) * 4;
                bo[0] = (float)o[0]; bo[1] = (float)o[1];
                bo[2] = (float)o[2]; bo[3] = (float)o[3];
            }
            __syncthreads();
            if (tid == 0) zbase += zpref[1023];
            __syncthreads();
            if (zbase >= needz) break;
        }
    }
}

// S: suppression matrix to global; 8 blocks/batch, 32 serial iters per wave.
__global__ __launch_bounds__(1024) void sup_build_kernel(const double* __restrict__ sbL,
                                                         const double* __restrict__ sbT,
                                                         const double* __restrict__ sbR,
                                                         const double* __restrict__ sbD,
                                                         const int* __restrict__ slab,
                                                         unsigned long long* __restrict__ bsup) {
    const int b = blockIdx.x >> 3;
    const int w = blockIdx.x & 7;
    const int tid = threadIdx.x;
    const int lane = tid & 63;
    const int wave = tid >> 6;
    __shared__ double Ls[KK], Ts[KK], Rs[KK], Ds[KK];
    __shared__ int Lb[KK];
    for (int i = tid; i < KK; i += 1024) {
        Ls[i] = sbL[b * KK + i];
        Ts[i] = sbT[b * KK + i];
        Rs[i] = sbR[b * KK + i];
        Ds[i] = sbD[b * KK + i];
        Lb[i] = slab[b * KK + i];
    }
    __syncthreads();
    const int j = w * 64 + lane;
    const bool jv = j < KK;
    double l2 = 0, t2 = 0, r2 = 0, d2 = 0, a2 = 0;
    int lj = -2;
    if (jv) {
        l2 = Ls[j]; t2 = Ts[j]; r2 = Rs[j]; d2 = Ds[j];
        lj = Lb[j];
        a2 = fmax(r2 - l2, 0.0) * fmax(d2 - t2, 0.0);
    }
    const int i0 = wave * 32;
    const int i1 = (i0 + 32 < KK) ? i0 + 32 : KK;
    for (int i = i0; i < i1; ++i) {
        double l1 = Ls[i], t1 = Ts[i], r1 = Rs[i], d1 = Ds[i];  // broadcast reads
        int li = Lb[i];
        bool sbit = false;
        if (jv && lj == li) {
            double a1 = fmax(r1 - l1, 0.0) * fmax(d1 - t1, 0.0);
            double iw = fmax(fmin(r1, r2) - fmax(l1, l2), 0.0);
            double ih = fmax(fmin(d1, d2) - fmax(t1, t2), 0.0);
            double inter = iw * ih;
            double uni = a1 + a2 - inter;
            sbit = inter > THRN * fmax(uni, 1e-9);  // iou > 0.5, exact
        }
        unsigned long long word = __ballot(sbit);
        if (lane == 0) bsup[((size_t)b * KK + i) * 8 + w] = word;
    }
}

// B: greedy NMS via wave-uniform E-mask (no LDS/shfl in dependent chain) + outputs.
__global__ __launch_bounds__(512) void supnms_kernel(const double* __restrict__ sdsc,
                                                     const int* __restrict__ slab,
                                                     const unsigned long long* __restrict__ bsup,
                                                     float* __restrict__ out) {
    const int b = blockIdx.x;
    const int tid = threadIdx.x;
    __shared__ unsigned long long sup[KK * 8];
    __shared__ double dscs[KK];
    __shared__ int labs[KK];
    __shared__ unsigned long long keepw[8];
    for (int t = tid; t < KK * 8; t += 512) sup[t] = bsup[(size_t)b * KK * 8 + t];
    for (int i = tid; i < KK; i += 512) {
        dscs[i] = sdsc[b * KK + i];
        labs[i] = slab[b * KK + i];
    }
    __syncthreads();
    if (tid < 64) {
        const int lane = tid;
        unsigned long long kept[8];
#pragma unroll
        for (int w = 0; w < 8; ++w) kept[w] = 0ULL;
#pragma unroll
        for (int c = 0; c < 8; ++c) {
            int i = c * 64 + lane;
            bool vi = false;
            unsigned long long sprev = 0ULL, myw = 0ULL;
            if (i < KK) {
                vi = dscs[i] > THRC;
#pragma unroll
                for (int w = 0; w < 8; ++w)
                    if (w < c) sprev |= sup[i * 8 + w] & kept[w];
                myw = sup[i * 8 + c];
            }
            unsigned long long E = __ballot(vi && sprev == 0ULL);  // undecided
            unsigned long long ck = 0ULL;
            while (E) {
                int j = __ffsll((unsigned long long)E) - 1;  // lowest undecided: kept
                ck |= 1ULL << j;
                unsigned long long S = __ballot(((myw >> j) & 1ULL) != 0);
                E &= ~S;
                E &= ~(1ULL << j);
            }
            kept[c] = ck;
        }
        if (lane == 0) {
#pragma unroll
            for (int w = 0; w < 8; ++w) keepw[w] = kept[w];
        }
    }
    __syncthreads();
    float* out_labels = out + BB * KK * 5;
    float* out_scores = out + BB * KK * 6;
    for (int i = tid; i < KK; i += 512) {
        bool keep = (keepw[i >> 6] >> (i & 63)) & 1ULL;
        out_labels[b * KK + i] = keep ? (float)labs[i] : -1.0f;
        out_scores[b * KK + i] = keep ? (float)dscs[i] : 0.0f;
    }
}

extern "C" void kernel_launch(void* const* d_in, const int* in_sizes, int n_in,
                              void* d_out, int out_size, void* d_ws, size_t ws_size,
                              hipStream_t stream) {
    const float* outs = (const float*)d_in[0];
    float* out = (float*)d_out;
    char* ws = (char*)d_ws;

    uint32_t* keys = (uint32_t*)ws;                                // 6.4 MB
    size_t off = (size_t)BB * NN * 4;
    unsigned long long* cand64 = (unsigned long long*)(ws + off);  // 256 KB
    off += (size_t)BB * NCAND * 8;
    double* cbox = (double*)(ws + off);                            // 1 MB
    off += (size_t)BB * NCAND * 4 * 8;
    double* sbL = (double*)(ws + off); off += (size_t)BB * KK * 8;
    double* sbT = (double*)(ws + off); off += (size_t)BB * KK * 8;
    double* sbR = (double*)(ws + off); off += (size_t)BB * KK * 8;
    double* sbD = (double*)(ws + off); off += (size_t)BB * KK * 8;
    double* sdsc = (double*)(ws + off); off += (size_t)BB * KK * 8;
    unsigned long long* bsup = (unsigned long long*)(ws + off);    // 512 KB
    off += (size_t)BB * KK * 8 * 8;
    size_t ghist_off = off;
    uint32_t* ghist = (uint32_t*)(ws + off);                       // 320 KB [memset]
    off += (size_t)BB * NBIN * 4;
    uint32_t* cnt = (uint32_t*)(ws + off);                         // 64 B   [memset]
    off += BB * 4;
    uint32_t* meta = (uint32_t*)(ws + off);                        // 128 B
    off += BB * 2 * 4;
    uint32_t* candidx = (uint32_t*)(ws + off);                     // 128 KB
    off += (size_t)BB * NCAND * 4;
    int* clab = (int*)(ws + off);                                  // 128 KB
    off += (size_t)BB * NCAND * 4;
    int* slab = (int*)(ws + off);                                  // 32 KB

    hipMemsetAsync(ws + ghist_off, 0, (size_t)BB * NBIN * 4 + BB * 4, stream);

    score_kernel<<<BB * BPB, 256, 0, stream>>>(outs, keys, ghist);
    scan_kernel<<<BB, 1024, 0, stream>>>(ghist, meta);
    gather_kernel<<<BB * GB3, 1024, 0, stream>>>(outs, keys, meta, cnt, cand64, candidx, cbox, clab);
    rank_kernel<<<BB, 1024, 0, stream>>>(outs, keys, cnt, cand64, candidx, cbox, clab,
                                         sdsc, sbL, sbT, sbR, sbD, slab, out);
    sup_build_kernel<<<BB * 8, 1024, 0, stream>>>(sbL, sbT, sbR, sbD, slab, bsup);
    supnms_kernel<<<BB, 512, 0, stream>>>(sdsc, slab, bsup, out);
}

// Round 8
// 254.325 us; speedup vs baseline: 1.5524x; 1.0255x over previous
//
#include <hip/hip_runtime.h>
#include <stdint.h>
#include <math.h>

#define BB 16
#define NN 100000
#define DD 25
#define CC 20
#define KK 500
#define NCAND 2048
#define NBIN 5120
#define EXPBASE (122 << 10)   // min f32 exponent field of a score in (0.049, 1)
#define BPB 391               // score blocks per batch (391*256 >= 100000)
#define GB3 98                // compact blocks per batch (98*1024 >= 100000)
#define DB 8                  // decode blocks per batch (8*256 = NCAND)
#define THRC 0.05
#define THRN 0.5

// Exact f64 score, replicating reference op order (candidates only).
__device__ __forceinline__ double score_f64(const float* row) {
    double m = (double)row[5];
#pragma unroll
    for (int i = 1; i < CC; ++i) m = fmax(m, (double)row[5 + i]);
    double s = 0.0;
#pragma unroll
    for (int i = 0; i < CC; ++i) s += exp((double)row[5 + i] - m);
    double conf = 1.0 / (1.0 + exp(-(double)row[4]));
    return conf * (1.0 / s);
}

// Fast f32 approx score (error ~32 ulp << histogram bin width of 8192 ulp).
__device__ __forceinline__ float score_f32(const float* row) {
    float m = row[5];
#pragma unroll
    for (int i = 1; i < CC; ++i) m = fmaxf(m, row[5 + i]);
    float s = 0.0f;
#pragma unroll
    for (int i = 0; i < CC; ++i) s += __expf(row[5 + i] - m);
    float conf = 1.0f / (1.0f + __expf(-row[4]));
    return conf / s;
}

__device__ __forceinline__ void decode_box(const float* row, double* o) {
    double cx = 1.0 / (1.0 + exp(-(double)row[0]));
    double cy = 1.0 / (1.0 + exp(-(double)row[1]));
    double w = 1.0 / (1.0 + exp(-(double)row[2]));
    double h = 1.0 / (1.0 + exp(-(double)row[3]));
    o[0] = cx - 0.5 * w;
    o[1] = cy - 0.5 * h;
    o[2] = cx + 0.5 * w;
    o[3] = cy + 0.5 * h;
}

__device__ __forceinline__ int argmax_cls(const float* row) {
    float mm = row[5];
    int am = 0;
#pragma unroll
    for (int c = 1; c < CC; ++c) {
        float v = row[5 + c];
        if (v > mm) { mm = v; am = c; }
    }
    return am;
}

// A: f32 approx keys + per-batch histogram (LDS pre-aggregated). Memory-bound.
__global__ __launch_bounds__(256) void score_kernel(const float* __restrict__ outs,
                                                    uint32_t* __restrict__ keys,
                                                    uint32_t* __restrict__ ghist) {
    __shared__ float tile[256 * DD];
    __shared__ uint32_t lhist[NBIN];
    const int b = blockIdx.x / BPB;
    const int lb = blockIdx.x % BPB;
    const int start = lb << 8;
    int nrows = NN - start;
    if (nrows > 256) nrows = 256;
    const float4* src = (const float4*)(outs + ((size_t)b * NN + start) * DD);
    const int nf4 = (nrows * DD) >> 2;
    float4* dst4 = (float4*)tile;
    for (int i = threadIdx.x; i < nf4; i += 256) dst4[i] = src[i];
    for (int i = threadIdx.x; i < NBIN; i += 256) lhist[i] = 0;
    __syncthreads();
    if ((int)threadIdx.x < nrows) {
        const float* row = tile + threadIdx.x * DD;
        float sc = score_f32(row);
        uint32_t key = 0;
        if (sc > 0.049f) {  // loose pre-mask; exact 0.05 decided in f64 later
            key = __float_as_uint(sc);
            int bin = (int)(key >> 13) - EXPBASE;
            bin = bin < 0 ? 0 : (bin > NBIN - 1 ? NBIN - 1 : bin);
            atomicAdd(&lhist[bin], 1u);
        }
        keys[(size_t)b * NN + start + threadIdx.x] = key;
    }
    __syncthreads();
    for (int i = threadIdx.x; i < NBIN; i += 256) {
        uint32_t v = lhist[i];
        if (v) atomicAdd(&ghist[b * NBIN + i], v);
    }
}

// A2: suffix-scan -> T'' = one bin below the count>=500 edge (safety margin).
__global__ __launch_bounds__(1024) void scan_kernel(const uint32_t* __restrict__ ghist,
                                                    uint32_t* __restrict__ meta) {
    const int b = blockIdx.x;
    const int tid = threadIdx.x;
    __shared__ uint32_t h[NBIN];
    __shared__ int sh_b;
    for (int i = tid; i < NBIN; i += 1024) h[i] = ghist[b * NBIN + i];
    __syncthreads();
    for (int off = 1; off < NBIN; off <<= 1) {
        uint32_t t0[5];
#pragma unroll
        for (int k = 0; k < 5; ++k) {
            int v = tid + k * 1024;
            uint32_t s = h[v];
            int u = v + off;
            if (u < NBIN) s += h[u];
            t0[k] = s;
        }
        __syncthreads();
#pragma unroll
        for (int k = 0; k < 5; ++k) h[tid + k * 1024] = t0[k];
        __syncthreads();
    }
#pragma unroll
    for (int k = 0; k < 5; ++k) {
        int v = tid + k * 1024;
        if (h[v] >= KK && (v == NBIN - 1 || h[v + 1] < KK)) sh_b = v;
    }
    __syncthreads();
    if (tid == 0) {
        uint32_t tot = h[0];
        int b2 = sh_b > 0 ? sh_b - 1 : sh_b;  // margin >> f32 approx error
        uint32_t T = (tot >= KK) ? (uint32_t)((EXPBASE + b2) << 13) : 1u;
        meta[2 * b] = T;
        meta[2 * b + 1] = tot;
    }
}

// A3a: cheap compaction only — append candidate indices (no f64 work here).
__global__ __launch_bounds__(1024) void compact_kernel(const uint32_t* __restrict__ keys,
                                                       const uint32_t* __restrict__ meta,
                                                       uint32_t* __restrict__ cnt,
                                                       uint32_t* __restrict__ candidx) {
    const int b = blockIdx.x / GB3;
    const int i = (blockIdx.x % GB3) * 1024 + threadIdx.x;
    if (i >= NN) return;
    uint32_t key = keys[(size_t)b * NN + i];
    if (key == 0 || key < meta[2 * b]) return;
    uint32_t pos = atomicAdd(&cnt[b], 1u);
    if (pos < NCAND) candidx[b * NCAND + pos] = (uint32_t)i;
}

// A3b: dense heavy decode — one thread per compacted candidate (no divergence).
__global__ __launch_bounds__(256) void decode_kernel(const float* __restrict__ outs,
                                                     const uint32_t* __restrict__ cnt,
                                                     const uint32_t* __restrict__ candidx,
                                                     unsigned long long* __restrict__ cand64,
                                                     double* __restrict__ cbox,
                                                     int* __restrict__ clab) {
    const int b = blockIdx.x / DB;
    const int c = (blockIdx.x % DB) * 256 + threadIdx.x;
    uint32_t cr = cnt[b];
    const int nc = (int)(cr < NCAND ? cr : NCAND);
    if (c >= nc) return;
    const uint32_t i = candidx[b * NCAND + c];
    const float* row = outs + ((size_t)b * NN + i) * DD;
    double sc = score_f64(row);
    cand64[b * NCAND + c] =
        (sc > THRC) ? (unsigned long long)__double_as_longlong(sc) : 0ULL;
    decode_box(row, cbox + ((size_t)b * NCAND + c) * 4);
    clab[b * NCAND + c] = argmax_cls(row);
}

// R: exact unique rank (f64 desc, idx asc) -> rank-ordered arrays + ids/boxes out.
__global__ __launch_bounds__(1024) void rank_kernel(const float* __restrict__ outs,
                                                    const uint32_t* __restrict__ keys,
                                                    const uint32_t* __restrict__ cnt,
                                                    const unsigned long long* __restrict__ cand64,
                                                    const uint32_t* __restrict__ candidx,
                                                    const double* __restrict__ cbox,
                                                    const int* __restrict__ clab,
                                                    double* __restrict__ sdsc,
                                                    double* __restrict__ sbL, double* __restrict__ sbT,
                                                    double* __restrict__ sbR, double* __restrict__ sbD,
                                                    int* __restrict__ slab,
                                                    float* __restrict__ out) {
    const int b = blockIdx.x;
    const int tid = threadIdx.x;
    __shared__ unsigned long long ckey[NCAND];
    __shared__ uint32_t cidx[NCAND];
    __shared__ uint32_t zpref[1024];
    __shared__ uint32_t zbase;
    float* out_ids = out;
    float* out_boxes = out + BB * KK;
    uint32_t cr = cnt[b];
    const int nc = (int)(cr < NCAND ? cr : NCAND);
    for (int i = tid; i < nc; i += 1024) {
        ckey[i] = cand64[b * NCAND + i];
        cidx[i] = candidx[b * NCAND + i];
    }
    __syncthreads();
    for (int c = tid; c < nc; c += 1024) {
        unsigned long long kc = ckey[c];
        uint32_t ic = cidx[c];
        int r = 0;
        int j = 0;
        for (; j + 8 <= nc; j += 8) {
#pragma unroll
            for (int u = 0; u < 8; ++u) {
                unsigned long long kj = ckey[j + u];
                uint32_t ij = cidx[j + u];
                r += (int)((kj > kc) || (kj == kc && ij < ic));
            }
        }
        for (; j < nc; ++j) {
            unsigned long long kj = ckey[j];
            uint32_t ij = cidx[j];
            r += (int)((kj > kc) || (kj == kc && ij < ic));
        }
        if (r < KK) {
            sdsc[b * KK + r] = __longlong_as_double((long long)kc);
            const double* cb = cbox + ((size_t)b * NCAND + c) * 4;
            sbL[b * KK + r] = cb[0];
            sbT[b * KK + r] = cb[1];
            sbR[b * KK + r] = cb[2];
            sbD[b * KK + r] = cb[3];
            slab[b * KK + r] = clab[b * NCAND + c];
            float* bo = out_boxes + ((size_t)b * KK + r) * 4;
            bo[0] = (float)cb[0]; bo[1] = (float)cb[1];
            bo[2] = (float)cb[2]; bo[3] = (float)cb[3];
        }
    }
    for (int i = tid; i < KK; i += 1024) out_ids[b * KK + i] = (float)b;
    // fallback (< 500 positives): lowest-index zero-key rows fill the rest
    if (nc < KK) {
        const uint32_t* kb = keys + (size_t)b * NN;
        if (tid == 0) zbase = 0;
        __syncthreads();
        const uint32_t needz = (uint32_t)(KK - nc);
        for (int c0 = 0; c0 < NN; c0 += 1024) {
            int i = c0 + tid;
            uint32_t z = (i < NN && kb[i] == 0) ? 1u : 0u;
            zpref[tid] = z;
            __syncthreads();
            for (int off = 1; off < 1024; off <<= 1) {
                uint32_t v = (tid >= off) ? zpref[tid - off] : 0u;
                __syncthreads();
                zpref[tid] += v;
                __syncthreads();
            }
            uint32_t pos = zbase + zpref[tid] - z;
            if (z && pos < needz) {
                int r = nc + (int)pos;
                const float* row = outs + ((size_t)b * NN + i) * DD;
                double o[4];
                decode_box(row, o);
                sdsc[b * KK + r] = 0.0;
                sbL[b * KK + r] = o[0]; sbT[b * KK + r] = o[1];
                sbR[b * KK + r] = o[2]; sbD[b * KK + r] = o[3];
                slab[b * KK + r] = argmax_cls(row);
                float* bo = out_boxes + ((size_t)b * KK + r) * 4;
                bo[0] = (float)o[0]; bo[1] = (float)o[1];
                bo[2] = (float)o[2]; bo[3] = (float)o[3];
            }
            __syncthreads();
            if (tid == 0) zbase += zpref[1023];
            __syncthreads();
            if (zbase >= needz) break;
        }
    }
}

// S: suppression matrix to global; 8 blocks/batch, 32 serial iters per wave.
__global__ __launch_bounds__(1024) void sup_build_kernel(const double* __restrict__ sbL,
                                                         const double* __restrict__ sbT,
                                                         const double* __restrict__ sbR,
                                                         const double* __restrict__ sbD,
                                                         const int* __restrict__ slab,
                                                         unsigned long long* __restrict__ bsup) {
    const int b = blockIdx.x >> 3;
    const int w = blockIdx.x & 7;
    const int tid = threadIdx.x;
    const int lane = tid & 63;
    const int wave = tid >> 6;
    __shared__ double Ls[KK], Ts[KK], Rs[KK], Ds[KK];
    __shared__ int Lb[KK];
    for (int i = tid; i < KK; i += 1024) {
        Ls[i] = sbL[b * KK + i];
        Ts[i] = sbT[b * KK + i];
        Rs[i] = sbR[b * KK + i];
        Ds[i] = sbD[b * KK + i];
        Lb[i] = slab[b * KK + i];
    }
    __syncthreads();
    const int j = w * 64 + lane;
    const bool jv = j < KK;
    double l2 = 0, t2 = 0, r2 = 0, d2 = 0, a2 = 0;
    int lj = -2;
    if (jv) {
        l2 = Ls[j]; t2 = Ts[j]; r2 = Rs[j]; d2 = Ds[j];
        lj = Lb[j];
        a2 = fmax(r2 - l2, 0.0) * fmax(d2 - t2, 0.0);
    }
    const int i0 = wave * 32;
    const int i1 = (i0 + 32 < KK) ? i0 + 32 : KK;
    for (int i = i0; i < i1; ++i) {
        double l1 = Ls[i], t1 = Ts[i], r1 = Rs[i], d1 = Ds[i];  // broadcast reads
        int li = Lb[i];
        bool sbit = false;
        if (jv && lj == li) {
            double a1 = fmax(r1 - l1, 0.0) * fmax(d1 - t1, 0.0);
            double iw = fmax(fmin(r1, r2) - fmax(l1, l2), 0.0);
            double ih = fmax(fmin(d1, d2) - fmax(t1, t2), 0.0);
            double inter = iw * ih;
            double uni = a1 + a2 - inter;
            sbit = inter > THRN * fmax(uni, 1e-9);  // iou > 0.5, exact
        }
        unsigned long long word = __ballot(sbit);
        if (lane == 0) bsup[((size_t)b * KK + i) * 8 + w] = word;
    }
}

// B: greedy NMS via wave-uniform E-mask (no LDS/shfl in dependent chain) + outputs.
__global__ __launch_bounds__(512) void supnms_kernel(const double* __restrict__ sdsc,
                                                     const int* __restrict__ slab,
                                                     const unsigned long long* __restrict__ bsup,
                                                     float* __restrict__ out) {
    const int b = blockIdx.x;
    const int tid = threadIdx.x;
    __shared__ unsigned long long sup[KK * 8];
    __shared__ double dscs[KK];
    __shared__ int labs[KK];
    __shared__ unsigned long long keepw[8];
    for (int t = tid; t < KK * 8; t += 512) sup[t] = bsup[(size_t)b * KK * 8 + t];
    for (int i = tid; i < KK; i += 512) {
        dscs[i] = sdsc[b * KK + i];
        labs[i] = slab[b * KK + i];
    }
    __syncthreads();
    if (tid < 64) {
        const int lane = tid;
        unsigned long long kept[8];
#pragma unroll
        for (int w = 0; w < 8; ++w) kept[w] = 0ULL;
#pragma unroll
        for (int c = 0; c < 8; ++c) {
            int i = c * 64 + lane;
            bool vi = false;
            unsigned long long sprev = 0ULL, myw = 0ULL;
            if (i < KK) {
                vi = dscs[i] > THRC;
#pragma unroll
                for (int w = 0; w < 8; ++w)
                    if (w < c) sprev |= sup[i * 8 + w] & kept[w];
                myw = sup[i * 8 + c];
            }
            unsigned long long E = __ballot(vi && sprev == 0ULL);  // undecided
            unsigned long long ck = 0ULL;
            while (E) {
                int j = __ffsll((unsigned long long)E) - 1;  // lowest undecided: kept
                ck |= 1ULL << j;
                unsigned long long S = __ballot(((myw >> j) & 1ULL) != 0);
                E &= ~S;
                E &= ~(1ULL << j);
            }
            kept[c] = ck;
        }
        if (lane == 0) {
#pragma unroll
            for (int w = 0; w < 8; ++w) keepw[w] = kept[w];
        }
    }
    __syncthreads();
    float* out_labels = out + BB * KK * 5;
    float* out_scores = out + BB * KK * 6;
    for (int i = tid; i < KK; i += 512) {
        bool keep = (keepw[i >> 6] >> (i & 63)) & 1ULL;
        out_labels[b * KK + i] = keep ? (float)labs[i] : -1.0f;
        out_scores[b * KK + i] = keep ? (float)dscs[i] : 0.0f;
    }
}

extern "C" void kernel_launch(void* const* d_in, const int* in_sizes, int n_in,
                              void* d_out, int out_size, void* d_ws, size_t ws_size,
                              hipStream_t stream) {
    const float* outs = (const float*)d_in[0];
    float* out = (float*)d_out;
    char* ws = (char*)d_ws;

    uint32_t* keys = (uint32_t*)ws;                                // 6.4 MB
    size_t off = (size_t)BB * NN * 4;
    unsigned long long* cand64 = (unsigned long long*)(ws + off);  // 256 KB
    off += (size_t)BB * NCAND * 8;
    double* cbox = (double*)(ws + off);                            // 1 MB
    off += (size_t)BB * NCAND * 4 * 8;
    double* sbL = (double*)(ws + off); off += (size_t)BB * KK * 8;
    double* sbT = (double*)(ws + off); off += (size_t)BB * KK * 8;
    double* sbR = (double*)(ws + off); off += (size_t)BB * KK * 8;
    double* sbD = (double*)(ws + off); off += (size_t)BB * KK * 8;
    double* sdsc = (double*)(ws + off); off += (size_t)BB * KK * 8;
    unsigned long long* bsup = (unsigned long long*)(ws + off);    // 512 KB
    off += (size_t)BB * KK * 8 * 8;
    size_t ghist_off = off;
    uint32_t* ghist = (uint32_t*)(ws + off);                       // 320 KB [memset]
    off += (size_t)BB * NBIN * 4;
    uint32_t* cnt = (uint32_t*)(ws + off);                         // 64 B   [memset]
    off += BB * 4;
    uint32_t* meta = (uint32_t*)(ws + off);                        // 128 B
    off += BB * 2 * 4;
    uint32_t* candidx = (uint32_t*)(ws + off);                     // 128 KB
    off += (size_t)BB * NCAND * 4;
    int* clab = (int*)(ws + off);                                  // 128 KB
    off += (size_t)BB * NCAND * 4;
    int* slab = (int*)(ws + off);                                  // 32 KB

    hipMemsetAsync(ws + ghist_off, 0, (size_t)BB * NBIN * 4 + BB * 4, stream);

    score_kernel<<<BB * BPB, 256, 0, stream>>>(outs, keys, ghist);
    scan_kernel<<<BB, 1024, 0, stream>>>(ghist, meta);
    compact_kernel<<<BB * GB3, 1024, 0, stream>>>(keys, meta, cnt, candidx);
    decode_kernel<<<BB * DB, 256, 0, stream>>>(outs, cnt, candidx, cand64, cbox, clab);
    rank_kernel<<<BB, 1024, 0, stream>>>(outs, keys, cnt, cand64, candidx, cbox, clab,
                                         sdsc, sbL, sbT, sbR, sbD, slab, out);
    sup_build_kernel<<<BB * 8, 1024, 0, stream>>>(sbL, sbT, sbR, sbD, slab, bsup);
    supnms_kernel<<<BB, 512, 0, stream>>>(sdsc, slab, bsup, out);
}

// Round 9
// 253.961 us; speedup vs baseline: 1.5547x; 1.0014x over previous
//
#include <hip/hip_runtime.h>
#include <stdint.h>
#include <math.h>

#define BB 16
#define NN 100000
#define DD 25
#define CC 20
#define KK 500
#define NCAND 2048
#define NBIN 5120
#define EXPBASE (122 << 10)   // min f32 exponent field of a score in (0.049, 1)
#define BPB 391               // score blocks per batch (391*256 >= 100000)
#define GB3 98                // compact blocks per batch (98*1024 >= 100000)
#define DB 8                  // decode blocks per batch (8*256 = NCAND)
#define THRC 0.05
#define THRN 0.5

// Zeroed region: ghist (BB*NBIN u32) + cnt (BB u32) = 81936 u32 = 20484 uint4.
#define ZERO_U4 ((BB * NBIN + BB) / 4)

__global__ __launch_bounds__(256) void zero_kernel(uint4* __restrict__ p) {
    int i = blockIdx.x * 256 + threadIdx.x;
    if (i < ZERO_U4) p[i] = make_uint4(0, 0, 0, 0);
}

// Exact f64 score, replicating reference op order (candidates only).
__device__ __forceinline__ double score_f64(const float* row) {
    double m = (double)row[5];
#pragma unroll
    for (int i = 1; i < CC; ++i) m = fmax(m, (double)row[5 + i]);
    double s = 0.0;
#pragma unroll
    for (int i = 0; i < CC; ++i) s += exp((double)row[5 + i] - m);
    double conf = 1.0 / (1.0 + exp(-(double)row[4]));
    return conf * (1.0 / s);
}

// Fast f32 approx score (error ~32 ulp << histogram bin width of 8192 ulp).
__device__ __forceinline__ float score_f32(const float* row) {
    float m = row[5];
#pragma unroll
    for (int i = 1; i < CC; ++i) m = fmaxf(m, row[5 + i]);
    float s = 0.0f;
#pragma unroll
    for (int i = 0; i < CC; ++i) s += __expf(row[5 + i] - m);
    float conf = 1.0f / (1.0f + __expf(-row[4]));
    return conf / s;
}

__device__ __forceinline__ void decode_box(const float* row, double* o) {
    double cx = 1.0 / (1.0 + exp(-(double)row[0]));
    double cy = 1.0 / (1.0 + exp(-(double)row[1]));
    double w = 1.0 / (1.0 + exp(-(double)row[2]));
    double h = 1.0 / (1.0 + exp(-(double)row[3]));
    o[0] = cx - 0.5 * w;
    o[1] = cy - 0.5 * h;
    o[2] = cx + 0.5 * w;
    o[3] = cy + 0.5 * h;
}

__device__ __forceinline__ int argmax_cls(const float* row) {
    float mm = row[5];
    int am = 0;
#pragma unroll
    for (int c = 1; c < CC; ++c) {
        float v = row[5 + c];
        if (v > mm) { mm = v; am = c; }
    }
    return am;
}

// A: f32 approx keys + per-batch histogram (LDS pre-aggregated). Memory-bound.
__global__ __launch_bounds__(256) void score_kernel(const float* __restrict__ outs,
                                                    uint32_t* __restrict__ keys,
                                                    uint32_t* __restrict__ ghist) {
    __shared__ float tile[256 * DD];
    __shared__ uint32_t lhist[NBIN];
    const int b = blockIdx.x / BPB;
    const int lb = blockIdx.x % BPB;
    const int start = lb << 8;
    int nrows = NN - start;
    if (nrows > 256) nrows = 256;
    const float4* src = (const float4*)(outs + ((size_t)b * NN + start) * DD);
    const int nf4 = (nrows * DD) >> 2;
    float4* dst4 = (float4*)tile;
    for (int i = threadIdx.x; i < nf4; i += 256) dst4[i] = src[i];
    for (int i = threadIdx.x; i < NBIN; i += 256) lhist[i] = 0;
    __syncthreads();
    if ((int)threadIdx.x < nrows) {
        const float* row = tile + threadIdx.x * DD;
        float sc = score_f32(row);
        uint32_t key = 0;
        if (sc > 0.049f) {  // loose pre-mask; exact 0.05 decided in f64 later
            key = __float_as_uint(sc);
            int bin = (int)(key >> 13) - EXPBASE;
            bin = bin < 0 ? 0 : (bin > NBIN - 1 ? NBIN - 1 : bin);
            atomicAdd(&lhist[bin], 1u);
        }
        keys[(size_t)b * NN + start + threadIdx.x] = key;
    }
    __syncthreads();
    for (int i = threadIdx.x; i < NBIN; i += 256) {
        uint32_t v = lhist[i];
        if (v) atomicAdd(&ghist[b * NBIN + i], v);
    }
}

// A2: suffix-scan -> T'' = one bin below the count>=500 edge (safety margin).
__global__ __launch_bounds__(1024) void scan_kernel(const uint32_t* __restrict__ ghist,
                                                    uint32_t* __restrict__ meta) {
    const int b = blockIdx.x;
    const int tid = threadIdx.x;
    __shared__ uint32_t h[NBIN];
    __shared__ int sh_b;
    for (int i = tid; i < NBIN; i += 1024) h[i] = ghist[b * NBIN + i];
    __syncthreads();
    for (int off = 1; off < NBIN; off <<= 1) {
        uint32_t t0[5];
#pragma unroll
        for (int k = 0; k < 5; ++k) {
            int v = tid + k * 1024;
            uint32_t s = h[v];
            int u = v + off;
            if (u < NBIN) s += h[u];
            t0[k] = s;
        }
        __syncthreads();
#pragma unroll
        for (int k = 0; k < 5; ++k) h[tid + k * 1024] = t0[k];
        __syncthreads();
    }
#pragma unroll
    for (int k = 0; k < 5; ++k) {
        int v = tid + k * 1024;
        if (h[v] >= KK && (v == NBIN - 1 || h[v + 1] < KK)) sh_b = v;
    }
    __syncthreads();
    if (tid == 0) {
        uint32_t tot = h[0];
        int b2 = sh_b > 0 ? sh_b - 1 : sh_b;  // margin >> f32 approx error
        uint32_t T = (tot >= KK) ? (uint32_t)((EXPBASE + b2) << 13) : 1u;
        meta[2 * b] = T;
        meta[2 * b + 1] = tot;
    }
}

// A3a: cheap compaction only — append candidate indices (no f64 work here).
__global__ __launch_bounds__(1024) void compact_kernel(const uint32_t* __restrict__ keys,
                                                       const uint32_t* __restrict__ meta,
                                                       uint32_t* __restrict__ cnt,
                                                       uint32_t* __restrict__ candidx) {
    const int b = blockIdx.x / GB3;
    const int i = (blockIdx.x % GB3) * 1024 + threadIdx.x;
    if (i >= NN) return;
    uint32_t key = keys[(size_t)b * NN + i];
    if (key == 0 || key < meta[2 * b]) return;
    uint32_t pos = atomicAdd(&cnt[b], 1u);
    if (pos < NCAND) candidx[b * NCAND + pos] = (uint32_t)i;
}

// A3b: dense heavy decode — one thread per compacted candidate (no divergence).
__global__ __launch_bounds__(256) void decode_kernel(const float* __restrict__ outs,
                                                     const uint32_t* __restrict__ cnt,
                                                     const uint32_t* __restrict__ candidx,
                                                     unsigned long long* __restrict__ cand64,
                                                     double* __restrict__ cbox,
                                                     int* __restrict__ clab) {
    const int b = blockIdx.x / DB;
    const int c = (blockIdx.x % DB) * 256 + threadIdx.x;
    uint32_t cr = cnt[b];
    const int nc = (int)(cr < NCAND ? cr : NCAND);
    if (c >= nc) return;
    const uint32_t i = candidx[b * NCAND + c];
    const float* row = outs + ((size_t)b * NN + i) * DD;
    double sc = score_f64(row);
    cand64[b * NCAND + c] =
        (sc > THRC) ? (unsigned long long)__double_as_longlong(sc) : 0ULL;
    decode_box(row, cbox + ((size_t)b * NCAND + c) * 4);
    clab[b * NCAND + c] = argmax_cls(row);
}

// R: exact unique rank (f64 desc, idx asc) -> rank-ordered arrays + ids/boxes out.
__global__ __launch_bounds__(1024) void rank_kernel(const float* __restrict__ outs,
                                                    const uint32_t* __restrict__ keys,
                                                    const uint32_t* __restrict__ cnt,
                                                    const unsigned long long* __restrict__ cand64,
                                                    const uint32_t* __restrict__ candidx,
                                                    const double* __restrict__ cbox,
                                                    const int* __restrict__ clab,
                                                    double* __restrict__ sdsc,
                                                    double* __restrict__ sbL, double* __restrict__ sbT,
                                                    double* __restrict__ sbR, double* __restrict__ sbD,
                                                    int* __restrict__ slab,
                                                    float* __restrict__ out) {
    const int b = blockIdx.x;
    const int tid = threadIdx.x;
    __shared__ unsigned long long ckey[NCAND];
    __shared__ uint32_t cidx[NCAND];
    __shared__ uint32_t zpref[1024];
    __shared__ uint32_t zbase;
    float* out_ids = out;
    float* out_boxes = out + BB * KK;
    uint32_t cr = cnt[b];
    const int nc = (int)(cr < NCAND ? cr : NCAND);
    for (int i = tid; i < nc; i += 1024) {
        ckey[i] = cand64[b * NCAND + i];
        cidx[i] = candidx[b * NCAND + i];
    }
    __syncthreads();
    for (int c = tid; c < nc; c += 1024) {
        unsigned long long kc = ckey[c];
        uint32_t ic = cidx[c];
        int r = 0;
        int j = 0;
        for (; j + 8 <= nc; j += 8) {
#pragma unroll
            for (int u = 0; u < 8; ++u) {
                unsigned long long kj = ckey[j + u];
                uint32_t ij = cidx[j + u];
                r += (int)((kj > kc) || (kj == kc && ij < ic));
            }
        }
        for (; j < nc; ++j) {
            unsigned long long kj = ckey[j];
            uint32_t ij = cidx[j];
            r += (int)((kj > kc) || (kj == kc && ij < ic));
        }
        if (r < KK) {
            sdsc[b * KK + r] = __longlong_as_double((long long)kc);
            const double* cb = cbox + ((size_t)b * NCAND + c) * 4;
            sbL[b * KK + r] = cb[0];
            sbT[b * KK + r] = cb[1];
            sbR[b * KK + r] = cb[2];
            sbD[b * KK + r] = cb[3];
            slab[b * KK + r] = clab[b * NCAND + c];
            float* bo = out_boxes + ((size_t)b * KK + r) * 4;
            bo[0] = (float)cb[0]; bo[1] = (float)cb[1];
            bo[2] = (float)cb[2]; bo[3] = (float)cb[3];
        }
    }
    for (int i = tid; i < KK; i += 1024) out_ids[b * KK + i] = (float)b;
    // fallback (< 500 positives): lowest-index zero-key rows fill the rest
    if (nc < KK) {
        const uint32_t* kb = keys + (size_t)b * NN;
        if (tid == 0) zbase = 0;
        __syncthreads();
        const uint32_t needz = (uint32_t)(KK - nc);
        for (int c0 = 0; c0 < NN; c0 += 1024) {
            int i = c0 + tid;
            uint32_t z = (i < NN && kb[i] == 0) ? 1u : 0u;
            zpref[tid] = z;
            __syncthreads();
            for (int off = 1; off < 1024; off <<= 1) {
                uint32_t v = (tid >= off) ? zpref[tid - off] : 0u;
                __syncthreads();
                zpref[tid] += v;
                __syncthreads();
            }
            uint32_t pos = zbase + zpref[tid] - z;
            if (z && pos < needz) {
                int r = nc + (int)pos;
                const float* row = outs + ((size_t)b * NN + i) * DD;
                double o[4];
                decode_box(row, o);
                sdsc[b * KK + r] = 0.0;
                sbL[b * KK + r] = o[0]; sbT[b * KK + r] = o[1];
                sbR[b * KK + r] = o[2]; sbD[b * KK + r] = o[3];
                slab[b * KK + r] = argmax_cls(row);
                float* bo = out_boxes + ((size_t)b * KK + r) * 4;
                bo[0] = (float)o[0]; bo[1] = (float)o[1];
                bo[2] = (float)o[2]; bo[3] = (float)o[3];
            }
            __syncthreads();
            if (tid == 0) zbase += zpref[1023];
            __syncthreads();
            if (zbase >= needz) break;
        }
    }
}

// S: suppression matrix to global; 8 blocks/batch, 32 serial iters per wave.
__global__ __launch_bounds__(1024) void sup_build_kernel(const double* __restrict__ sbL,
                                                         const double* __restrict__ sbT,
                                                         const double* __restrict__ sbR,
                                                         const double* __restrict__ sbD,
                                                         const int* __restrict__ slab,
                                                         unsigned long long* __restrict__ bsup) {
    const int b = blockIdx.x >> 3;
    const int w = blockIdx.x & 7;
    const int tid = threadIdx.x;
    const int lane = tid & 63;
    const int wave = tid >> 6;
    __shared__ double Ls[KK], Ts[KK], Rs[KK], Ds[KK];
    __shared__ int Lb[KK];
    for (int i = tid; i < KK; i += 1024) {
        Ls[i] = sbL[b * KK + i];
        Ts[i] = sbT[b * KK + i];
        Rs[i] = sbR[b * KK + i];
        Ds[i] = sbD[b * KK + i];
        Lb[i] = slab[b * KK + i];
    }
    __syncthreads();
    const int j = w * 64 + lane;
    const bool jv = j < KK;
    double l2 = 0, t2 = 0, r2 = 0, d2 = 0, a2 = 0;
    int lj = -2;
    if (jv) {
        l2 = Ls[j]; t2 = Ts[j]; r2 = Rs[j]; d2 = Ds[j];
        lj = Lb[j];
        a2 = fmax(r2 - l2, 0.0) * fmax(d2 - t2, 0.0);
    }
    const int i0 = wave * 32;
    const int i1 = (i0 + 32 < KK) ? i0 + 32 : KK;
    for (int i = i0; i < i1; ++i) {
        double l1 = Ls[i], t1 = Ts[i], r1 = Rs[i], d1 = Ds[i];  // broadcast reads
        int li = Lb[i];
        bool sbit = false;
        if (jv && lj == li) {
            double a1 = fmax(r1 - l1, 0.0) * fmax(d1 - t1, 0.0);
            double iw = fmax(fmin(r1, r2) - fmax(l1, l2), 0.0);
            double ih = fmax(fmin(d1, d2) - fmax(t1, t2), 0.0);
            double inter = iw * ih;
            double uni = a1 + a2 - inter;
            sbit = inter > THRN * fmax(uni, 1e-9);  // iou > 0.5, exact
        }
        unsigned long long word = __ballot(sbit);
        if (lane == 0) bsup[((size_t)b * KK + i) * 8 + w] = word;
    }
}

// B: greedy NMS via wave-uniform E-mask (no LDS/shfl in dependent chain) + outputs.
__global__ __launch_bounds__(512) void supnms_kernel(const double* __restrict__ sdsc,
                                                     const int* __restrict__ slab,
                                                     const unsigned long long* __restrict__ bsup,
                                                     float* __restrict__ out) {
    const int b = blockIdx.x;
    const int tid = threadIdx.x;
    __shared__ unsigned long long sup[KK * 8];
    __shared__ double dscs[KK];
    __shared__ int labs[KK];
    __shared__ unsigned long long keepw[8];
    for (int t = tid; t < KK * 8; t += 512) sup[t] = bsup[(size_t)b * KK * 8 + t];
    for (int i = tid; i < KK; i += 512) {
        dscs[i] = sdsc[b * KK + i];
        labs[i] = slab[b * KK + i];
    }
    __syncthreads();
    if (tid < 64) {
        const int lane = tid;
        unsigned long long kept[8];
#pragma unroll
        for (int w = 0; w < 8; ++w) kept[w] = 0ULL;
#pragma unroll
        for (int c = 0; c < 8; ++c) {
            int i = c * 64 + lane;
            bool vi = false;
            unsigned long long sprev = 0ULL, myw = 0ULL;
            if (i < KK) {
                vi = dscs[i] > THRC;
#pragma unroll
                for (int w = 0; w < 8; ++w)
                    if (w < c) sprev |= sup[i * 8 + w] & kept[w];
                myw = sup[i * 8 + c];
            }
            unsigned long long E = __ballot(vi && sprev == 0ULL);  // undecided
            unsigned long long ck = 0ULL;
            while (E) {
                int j = __ffsll((unsigned long long)E) - 1;  // lowest undecided: kept
                ck |= 1ULL << j;
                unsigned long long S = __ballot(((myw >> j) & 1ULL) != 0);
                E &= ~S;
                E &= ~(1ULL << j);
            }
            kept[c] = ck;
        }
        if (lane == 0) {
#pragma unroll
            for (int w = 0; w < 8; ++w) keepw[w] = kept[w];
        }
    }
    __syncthreads();
    float* out_labels = out + BB * KK * 5;
    float* out_scores = out + BB * KK * 6;
    for (int i = tid; i < KK; i += 512) {
        bool keep = (keepw[i >> 6] >> (i & 63)) & 1ULL;
        out_labels[b * KK + i] = keep ? (float)labs[i] : -1.0f;
        out_scores[b * KK + i] = keep ? (float)dscs[i] : 0.0f;
    }
}

extern "C" void kernel_launch(void* const* d_in, const int* in_sizes, int n_in,
                              void* d_out, int out_size, void* d_ws, size_t ws_size,
                              hipStream_t stream) {
    const float* outs = (const float*)d_in[0];
    float* out = (float*)d_out;
    char* ws = (char*)d_ws;

    uint32_t* keys = (uint32_t*)ws;                                // 6.4 MB
    size_t off = (size_t)BB * NN * 4;
    unsigned long long* cand64 = (unsigned long long*)(ws + off);  // 256 KB
    off += (size_t)BB * NCAND * 8;
    double* cbox = (double*)(ws + off);                            // 1 MB
    off += (size_t)BB * NCAND * 4 * 8;
    double* sbL = (double*)(ws + off); off += (size_t)BB * KK * 8;
    double* sbT = (double*)(ws + off); off += (size_t)BB * KK * 8;
    double* sbR = (double*)(ws + off); off += (size_t)BB * KK * 8;
    double* sbD = (double*)(ws + off); off += (size_t)BB * KK * 8;
    double* sdsc = (double*)(ws + off); off += (size_t)BB * KK * 8;
    unsigned long long* bsup = (unsigned long long*)(ws + off);    // 512 KB
    off += (size_t)BB * KK * 8 * 8;
    size_t ghist_off = off;
    uint32_t* ghist = (uint32_t*)(ws + off);                       // 320 KB [zeroed]
    off += (size_t)BB * NBIN * 4;
    uint32_t* cnt = (uint32_t*)(ws + off);                         // 64 B   [zeroed]
    off += BB * 4;
    uint32_t* meta = (uint32_t*)(ws + off);                        // 128 B
    off += BB * 2 * 4;
    uint32_t* candidx = (uint32_t*)(ws + off);                     // 128 KB
    off += (size_t)BB * NCAND * 4;
    int* clab = (int*)(ws + off);                                  // 128 KB
    off += (size_t)BB * NCAND * 4;
    int* slab = (int*)(ws + off);                                  // 32 KB

    zero_kernel<<<(ZERO_U4 + 255) / 256, 256, 0, stream>>>((uint4*)(ws + ghist_off));
    score_kernel<<<BB * BPB, 256, 0, stream>>>(outs, keys, ghist);
    scan_kernel<<<BB, 1024, 0, stream>>>(ghist, meta);
    compact_kernel<<<BB * GB3, 1024, 0, stream>>>(keys, meta, cnt, candidx);
    decode_kernel<<<BB * DB, 256, 0, stream>>>(outs, cnt, candidx, cand64, cbox, clab);
    rank_kernel<<<BB, 1024, 0, stream>>>(outs, keys, cnt, cand64, candidx, cbox, clab,
                                         sdsc, sbL, sbT, sbR, sbD, slab, out);
    sup_build_kernel<<<BB * 8, 1024, 0, stream>>>(sbL, sbT, sbR, sbD, slab, bsup);
    supnms_kernel<<<BB, 512, 0, stream>>>(sdsc, slab, bsup, out);
}